// Round 5
// baseline (1157.390 us; speedup 1.0000x reference)
//
#include <hip/hip_runtime.h>
#include <cmath>
#include <cstdint>

// ---------------- static configuration ----------------
// B=32, T=4096, C=3, 128 scales, out 224x224, N_PSI=4096, pad=2047.
// sig = c*32 + b  (96 signals), padded signal length 8190 (store 8192).
// Composite kernel per (scale, class): class 0..6 = interior phase (w mod 7),
// class 7 = w==0 (left-clipped), class 8 = w==223 (right-clipped).
// H rows: [160 zero guard][<=3308 data, 4-aligned][>=308 zero guard], stride 3776 floats.
// xp stored interleaved: xp4[m>>2][sig][m&3] -> one global_load_dwordx4 per 4 m.
// Main kernel: block = (scale, 4 w's, m-piece of 1024); scale-major dispatch
// (heavy scales first) keeps co-resident blocks on the same ~135 KB of H (L2-hot).
// Round 5: H loads moved OFF the scalar pipe. Wave-uniform H addresses lowered
// to s_load_dwordx4; 8 quads = 64 SGPRs payload and the ~102-SGPR/wave file
// cannot hold a depth-2 pipeline, so the compiler drained lgkmcnt every
// iteration (VALUBusy pinned at ~25%, rounds 3-4 identical). We add a
// runtime-zero, lane-addressed value `dzi` to the H pointers so they are not
// provably uniform -> global_load_dwordx4 (same-address broadcast, 1
// transaction) -> depth-2 VGPR pipeline with ~20 loads in flight.

constexpr int C_TP     = 8190;
constexpr int C_XROWS  = 8192;   // time rows in xp
constexpr int C_SIGP   = 128;    // padded signals (96 real)
constexpr long long C_HSTRIDE = 3776;
constexpr int C_HGUARD = 160;
constexpr int C_NCLS   = 9;
constexpr int C_RW     = 4;      // w's per block
constexpr int C_NCH    = 56;     // 224 / C_RW
constexpr int C_NW     = 224;
constexpr int C_M      = 1024;   // m per piece
constexpr int C_NP     = 4;      // max pieces

// Replicate numpy: scales = logspace(log10(2), log10(204), 128).astype(f32);
// K = ceil(16*s + 1); d = (4094-K)//2; a = s * (16/4095) in double.
__device__ __forceinline__ void scale_params(int i, float& s32, int& K, int& d, double& a) {
  const double l2   = log10(2.0);
  const double l204 = log10(204.0);
  double step = (l204 - l2) / 127.0;
  double e = (i == 127) ? l204 : ((double)i * step + l2);
  double sv = pow(10.0, e);
  s32 = (float)sv;
  double sp = (double)s32;
  K = (int)ceil(sp * 16.0 + 1.0);
  d = (4094 - K) >> 1;
  a = sp * (16.0 / 4095.0);
}

// ---------------- build reflect-padded, interleaved signals ----------------
__global__ void k_build_xp(const float* __restrict__ x, float* __restrict__ xp4) {
  int idx = blockIdx.x * blockDim.x + threadIdx.x;   // 8192*128 threads
  int j    = idx & 3;
  int sig  = (idx >> 2) & 127;
  int mblk = idx >> 9;
  int p    = mblk * 4 + j;
  float val = 0.f;
  if (sig < 96 && p < C_TP) {
    int c = sig >> 5;
    int b = sig & 31;
    int t = p - 2047;
    if (t < 0) t = -t;                 // x[2047-p]
    else if (t > 4095) t = 8190 - t;   // x[10237-p]
    val = x[(b * 4096 + t) * 3 + c];
  }
  xp4[idx] = val;
}

// ---------------- zero OT (atomic accumulation target) ----------------
__global__ void k_zero(float* __restrict__ p, int n4) {
  int idx = blockIdx.x * blockDim.x + threadIdx.x;
  if (idx < n4) ((float4*)p)[idx] = make_float4(0.f, 0.f, 0.f, 0.f);
}

// ---------------- build composite kernels H ----------------
__global__ __launch_bounds__(256) void k_build_H(const float* __restrict__ int_psi,
                                                 float* __restrict__ Hbuf,
                                                 int* __restrict__ meta) {
  int i   = blockIdx.x;   // scale
  int cls = blockIdx.y;   // class

  float s32; int K, d; double a;
  scale_params(i, s32, K, d, a);

  int wr = (cls < 7) ? ((cls == 0) ? 7 : cls) : ((cls == 7) ? 0 : 223);
  double ks = 4096.0 / 224.0;
  double sf = ((double)wr + 0.5) * ks - 0.5;
  int t_lo = (int)floor(sf - ks) + 1;
  int t_hi = (int)ceil(sf + ks) - 1;
  if (t_lo < 0) t_lo = 0;
  if (t_hi > 4095) t_hi = 4095;
  int nt  = t_hi - t_lo + 1;   // <= 37
  int npv = nt + 1;            // conv-point weights

  __shared__ double Wt_sh[40];
  __shared__ double v_sh[64];
  __shared__ float  kern_sh[3352];

  // zero this block's full row
  float* rowFull = Hbuf + (long long)(i * C_NCLS + cls) * C_HSTRIDE;
  for (int q = threadIdx.x; q < (int)C_HSTRIDE; q += 256) rowFull[q] = 0.f;

  if (threadIdx.x == 0) {
    double Z = 0.0;
    for (int t = 0; t < nt; ++t) {
      double wv = 1.0 - fabs(sf - (double)(t + t_lo)) / ks;
      if (wv < 0.0) wv = 0.0;
      Wt_sh[t] = wv; Z += wv;
    }
    for (int t = 0; t < nt; ++t) Wt_sh[t] = Wt_sh[t] / Z;
    double sq = sqrt((double)s32);
    // v[p_lo + q] = -sqrt(s) * (Wt[q-1] - Wt[q])
    for (int q = 0; q <= nt; ++q) {
      double wm1 = (q >= 1)  ? Wt_sh[q - 1] : 0.0;
      double w0  = (q < nt)  ? Wt_sh[q]     : 0.0;
      v_sh[q] = -sq * (wm1 - w0);
    }
  }

  // flipped gathered wavelet: kernW[tau] = int_psi[clip(floor((K-1-tau)/a))]
  float* kernp = kern_sh + 40;
  int fillN = K + 80;
  for (int q = threadIdx.x; q < fillN; q += 256) {
    int tau = q - 40;
    float kv = 0.f;
    if (tau >= 0 && tau < K) {
      int u = K - 1 - tau;
      int jj = (int)floor((double)u / a);
      jj = jj < 0 ? 0 : (jj > 4095 ? 4095 : jj);
      kv = int_psi[jj];
    }
    kern_sh[q] = kv;
  }
  __syncthreads();

  int p_lo = t_lo + d;
  int Lh   = K + npv - 1;
  int kr   = (cls == 0) ? 1 : ((cls == 8) ? 31 : 0);
  int off0 = p_lo - 128 * kr;
  int shift = off0 & 3;
  int offA  = off0 - shift;
  int rowLen = (shift + Lh + 3) & ~3;

  float* row = Hbuf + (long long)(i * C_NCLS + cls) * C_HSTRIDE + C_HGUARD;
  for (int q = threadIdx.x; q < Lh; q += 256) {
    double acc = 0.0;
    for (int t = 0; t < npv; ++t) acc += v_sh[t] * (double)kernp[q - t];
    row[shift + q] = (float)acc;
  }
  if (threadIdx.x == 0) {
    meta[(i * C_NCLS + cls) * 2 + 0] = offA;
    meta[(i * C_NCLS + cls) * 2 + 1] = rowLen;
  }
}

// ---------------- main: OT[scale][w][sig] += sum_{m in piece} xp[m][sig]*H_w[m] ----------
// grid (piece, chunk, scale'), scale' reversed so heavy scales dispatch first.
__global__ __launch_bounds__(128, 4) void k_cwt_main(const float4* __restrict__ xp4,
                                                     const float* __restrict__ Hbuf,
                                                     const int* __restrict__ meta,
                                                     float* __restrict__ OT) {
  int piece = blockIdx.x;           // 0..3
  int chunk = blockIdx.y;           // 0..55
  int i     = 127 - blockIdx.z;     // heavy scales first
  int sig   = threadIdx.x;          // 0..127 (>=96 compute zeros)

  // Runtime zero loaded from a guaranteed-zero xp4 cell at a lane-dependent
  // address. Value is 0 for every lane, but the compiler cannot prove it, so
  // H pointers below are divergent -> vector loads (global_load_dwordx4,
  // same-address broadcast) instead of s_load -> depth-2 pipeline possible.
  int dzi = (int)((const float*)xp4)[2047 * 512 + sig * 4 + 3];

  float acc[C_RW];
  const float* P[C_RW];
  int U0 = 0x7fffffff, U1 = 0;
#pragma unroll
  for (int j = 0; j < C_RW; ++j) {
    acc[j] = 0.f;
    int w = chunk * C_RW + j;
    int cls = (w == 0) ? 7 : ((w == 223) ? 8 : (w % 7));
    int k = w / 7;
    int base = i * C_NCLS + cls;
    int offA = meta[base * 2 + 0];
    int rl   = meta[base * 2 + 1];
    int start = offA + 128 * k;           // 4-aligned by construction
    if (start < U0) U0 = start;
    if (start + rl > U1) U1 = start + rl;
    P[j] = Hbuf + ((long long)base * C_HSTRIDE + C_HGUARD - start) + dzi;
  }

  int m0 = U0 + piece * C_M;
  int m1 = m0 + C_M; if (m1 > U1) m1 = U1;
  if (m0 >= m1) return;

  // ---- software pipeline: x depth-2, H depth-1 ahead, all in VGPRs ----
  // All overreads land in H zero-guards / within xp4 (max m index < 8192-24).
  const float4* xr = xp4 + ((long long)(m0 >> 2) * C_SIGP + sig);
  float4 xa0 = xr[0];
  float4 xb0 = xr[C_SIGP];
  float4 xa1 = xr[2 * C_SIGP];
  float4 xb1 = xr[3 * C_SIGP];
  xr += 4 * C_SIGP;

  float4 ha0[C_RW], hb0[C_RW];
#pragma unroll
  for (int j = 0; j < C_RW; ++j) {
    ha0[j] = *(const float4*)(P[j] + m0);      // broadcast vector load
    hb0[j] = *(const float4*)(P[j] + m0 + 4);
  }

  for (int m = m0; m < m1; m += 8) {
    // issue loads for m+16 (x) and m+8 (H) before computing with current regs
    float4 xa2 = xr[0];
    float4 xb2 = xr[C_SIGP];
    xr += 2 * C_SIGP;
    float4 ha1[C_RW], hb1[C_RW];
#pragma unroll
    for (int j = 0; j < C_RW; ++j) {
      ha1[j] = *(const float4*)(P[j] + m + 8);
      hb1[j] = *(const float4*)(P[j] + m + 12);
    }
#pragma unroll
    for (int j = 0; j < C_RW; ++j) {
      acc[j] += xa0.x * ha0[j].x + xa0.y * ha0[j].y + xa0.z * ha0[j].z + xa0.w * ha0[j].w;
      acc[j] += xb0.x * hb0[j].x + xb0.y * hb0[j].y + xb0.z * hb0[j].z + xb0.w * hb0[j].w;
    }
    // rotate
    xa0 = xa1; xb0 = xb1; xa1 = xa2; xb1 = xb2;
#pragma unroll
    for (int j = 0; j < C_RW; ++j) { ha0[j] = ha1[j]; hb0[j] = hb1[j]; }
  }

#pragma unroll
  for (int j = 0; j < C_RW; ++j) {
    int w = chunk * C_RW + j;
    atomicAdd(&OT[((long long)i * C_NW + w) * C_SIGP + sig], acc[j]);
  }
}

// ---------------- final: scale-dim bilinear upsample 128->224 + layout ----------------
__global__ __launch_bounds__(256) void k_final(const float* __restrict__ OT,
                                               float* __restrict__ out) {
  int wt = blockIdx.x;    // 0..27
  int h  = blockIdx.y;    // 0..223

  float inv = 128.0f / 224.0f;               // f32 like jax
  float sg = ((float)h + 0.5f) * inv - 0.5f;
  float sgf = floorf(sg);
  int s0 = (int)sgf;
  float fr = sg - sgf;
  int r0, r1;
  if (s0 < 0)        { r0 = 0;   r1 = 0;   fr = 0.f; }
  else if (s0 >= 127){ r0 = 127; r1 = 127; fr = 0.f; }
  else               { r0 = s0;  r1 = s0 + 1; }

  __shared__ float sh0[8 * 132];
  __shared__ float sh1[8 * 132];
  for (int q = threadIdx.x; q < 1024; q += 256) {
    int wp  = q >> 7;
    int sg2 = q & 127;
    int wg  = wt * 8 + wp;
    sh0[wp * 132 + sg2] = OT[((long long)r0 * C_NW + wg) * C_SIGP + sg2];
    sh1[wp * 132 + sg2] = OT[((long long)r1 * C_NW + wg) * C_SIGP + sg2];
  }
  __syncthreads();

  int b  = threadIdx.x >> 3;    // 0..31
  int wp = threadIdx.x & 7;     // 0..7
  int obase = ((b * 224 + h) * 224 + wt * 8 + wp) * 3;
#pragma unroll
  for (int c = 0; c < 3; ++c) {
    int sidx = wp * 132 + c * 32 + b;
    float a0 = sh0[sidx];
    float a1 = sh1[sidx];
    out[obase + c] = (1.0f - fr) * a0 + fr * a1;
  }
}

// ---------------- launch ----------------
extern "C" void kernel_launch(void* const* d_in, const int* in_sizes, int n_in,
                              void* d_out, int out_size, void* d_ws, size_t ws_size,
                              hipStream_t stream) {
  const float* x       = (const float*)d_in[0];   // (32,4096,3) f32
  const float* int_psi = (const float*)d_in[1];   // (4096,) f32
  float* out = (float*)d_out;

  // workspace layout: xp4 (4 MB) | Hbuf (17.4 MB) | meta (9 KB) | OT (14.7 MB)
  float* xp4  = (float*)d_ws;                                   // 8192*128 floats
  float* Hbuf = xp4 + (long long)C_XROWS * C_SIGP;              // 1152*3776 floats
  int*   meta = (int*)(Hbuf + (long long)128 * C_NCLS * C_HSTRIDE); // 2304 ints
  float* OT   = (float*)(meta + 2304);                          // 128*224*128 floats

  int otN = 128 * C_NW * C_SIGP;
  k_zero<<<dim3(otN / 4 / 256), dim3(256), 0, stream>>>(OT, otN / 4);
  k_build_xp<<<dim3((C_XROWS * C_SIGP) / 256), dim3(256), 0, stream>>>(x, xp4);
  k_build_H<<<dim3(128, C_NCLS), dim3(256), 0, stream>>>(int_psi, Hbuf, meta);
  k_cwt_main<<<dim3(C_NP, C_NCH, 128), dim3(128), 0, stream>>>((const float4*)xp4, Hbuf, meta, OT);
  k_final<<<dim3(28, 224), dim3(256), 0, stream>>>(OT, out);
}

// Round 6
// 278.840 us; speedup vs baseline: 4.1507x; 4.1507x over previous
//
#include <hip/hip_runtime.h>
#include <cmath>
#include <cstdint>

// ---------------- static configuration ----------------
// B=32, T=4096, C=3, 128 scales, out 224x224, N_PSI=4096, pad=2047.
// sig = c*32 + b  (96 signals), padded signal length 8190 (store 8192).
// Composite kernel per (scale, class): class 0..6 = interior phase (w mod 7),
// class 7 = w==0 (left-clipped), class 8 = w==223 (right-clipped).
// H rows: [160 zero guard][<=3308 data, 4-aligned][>=308 zero guard], stride 3776 floats.
// xp stored interleaved: xp4[m>>2][sig][m&3] -> one global_load_dwordx4 per 4 m.
//
// Round 6: H comes through LDS. History: scalar s_load path (r3/r4) pins at
// VALUBusy ~25% because 8 quads = 64 SGPRs payload can't be double-buffered in
// a ~102-SGPR file -> full lgkmcnt drain per iteration (~300cy scalar-L2).
// Vector-broadcast H (r5) was worse: H and x share vmcnt -> 10-deep vmcnt(0)
// drain (~3x slower). LDS staging splits the streams onto INDEPENDENT wait
// counters: x on vmcnt, H on lgkmcnt, and the compiler emits fine-grained
// lgkmcnt for ds_read chains. Broadcast ds_read (all lanes same addr) is
// conflict-free. C_M=512 -> 8.4 KB LDS/block -> 16 blocks/CU (32 waves) for TLP.

constexpr int C_TP     = 8190;
constexpr int C_XROWS  = 8192;   // time rows in xp
constexpr int C_SIGP   = 128;    // padded signals (96 real)
constexpr long long C_HSTRIDE = 3776;
constexpr int C_HGUARD = 160;
constexpr int C_NCLS   = 9;
constexpr int C_RW     = 4;      // w's per block
constexpr int C_NCH    = 56;     // 224 / C_RW
constexpr int C_NW     = 224;
constexpr int C_M      = 512;    // m per piece
constexpr int C_NP     = 7;      // max pieces: ceil(~3450/512)
constexpr int C_SL4    = 132;    // staged float4 per row: (512+16)/4 + slack

// Replicate numpy: scales = logspace(log10(2), log10(204), 128).astype(f32);
// K = ceil(16*s + 1); d = (4094-K)//2; a = s * (16/4095) in double.
__device__ __forceinline__ void scale_params(int i, float& s32, int& K, int& d, double& a) {
  const double l2   = log10(2.0);
  const double l204 = log10(204.0);
  double step = (l204 - l2) / 127.0;
  double e = (i == 127) ? l204 : ((double)i * step + l2);
  double sv = pow(10.0, e);
  s32 = (float)sv;
  double sp = (double)s32;
  K = (int)ceil(sp * 16.0 + 1.0);
  d = (4094 - K) >> 1;
  a = sp * (16.0 / 4095.0);
}

// ---------------- build reflect-padded, interleaved signals ----------------
__global__ void k_build_xp(const float* __restrict__ x, float* __restrict__ xp4) {
  int idx = blockIdx.x * blockDim.x + threadIdx.x;   // 8192*128 threads
  int j    = idx & 3;
  int sig  = (idx >> 2) & 127;
  int mblk = idx >> 9;
  int p    = mblk * 4 + j;
  float val = 0.f;
  if (sig < 96 && p < C_TP) {
    int c = sig >> 5;
    int b = sig & 31;
    int t = p - 2047;
    if (t < 0) t = -t;                 // x[2047-p]
    else if (t > 4095) t = 8190 - t;   // x[10237-p]
    val = x[(b * 4096 + t) * 3 + c];
  }
  xp4[idx] = val;
}

// ---------------- zero OT (atomic accumulation target) ----------------
__global__ void k_zero(float* __restrict__ p, int n4) {
  int idx = blockIdx.x * blockDim.x + threadIdx.x;
  if (idx < n4) ((float4*)p)[idx] = make_float4(0.f, 0.f, 0.f, 0.f);
}

// ---------------- build composite kernels H ----------------
__global__ __launch_bounds__(256) void k_build_H(const float* __restrict__ int_psi,
                                                 float* __restrict__ Hbuf,
                                                 int* __restrict__ meta) {
  int i   = blockIdx.x;   // scale
  int cls = blockIdx.y;   // class

  float s32; int K, d; double a;
  scale_params(i, s32, K, d, a);

  int wr = (cls < 7) ? ((cls == 0) ? 7 : cls) : ((cls == 7) ? 0 : 223);
  double ks = 4096.0 / 224.0;
  double sf = ((double)wr + 0.5) * ks - 0.5;
  int t_lo = (int)floor(sf - ks) + 1;
  int t_hi = (int)ceil(sf + ks) - 1;
  if (t_lo < 0) t_lo = 0;
  if (t_hi > 4095) t_hi = 4095;
  int nt  = t_hi - t_lo + 1;   // <= 37
  int npv = nt + 1;            // conv-point weights

  __shared__ double Wt_sh[40];
  __shared__ double v_sh[64];
  __shared__ float  kern_sh[3352];

  // zero this block's full row
  float* rowFull = Hbuf + (long long)(i * C_NCLS + cls) * C_HSTRIDE;
  for (int q = threadIdx.x; q < (int)C_HSTRIDE; q += 256) rowFull[q] = 0.f;

  if (threadIdx.x == 0) {
    double Z = 0.0;
    for (int t = 0; t < nt; ++t) {
      double wv = 1.0 - fabs(sf - (double)(t + t_lo)) / ks;
      if (wv < 0.0) wv = 0.0;
      Wt_sh[t] = wv; Z += wv;
    }
    for (int t = 0; t < nt; ++t) Wt_sh[t] = Wt_sh[t] / Z;
    double sq = sqrt((double)s32);
    // v[p_lo + q] = -sqrt(s) * (Wt[q-1] - Wt[q])
    for (int q = 0; q <= nt; ++q) {
      double wm1 = (q >= 1)  ? Wt_sh[q - 1] : 0.0;
      double w0  = (q < nt)  ? Wt_sh[q]     : 0.0;
      v_sh[q] = -sq * (wm1 - w0);
    }
  }

  // flipped gathered wavelet: kernW[tau] = int_psi[clip(floor((K-1-tau)/a))]
  float* kernp = kern_sh + 40;
  int fillN = K + 80;
  for (int q = threadIdx.x; q < fillN; q += 256) {
    int tau = q - 40;
    float kv = 0.f;
    if (tau >= 0 && tau < K) {
      int u = K - 1 - tau;
      int jj = (int)floor((double)u / a);
      jj = jj < 0 ? 0 : (jj > 4095 ? 4095 : jj);
      kv = int_psi[jj];
    }
    kern_sh[q] = kv;
  }
  __syncthreads();

  int p_lo = t_lo + d;
  int Lh   = K + npv - 1;
  int kr   = (cls == 0) ? 1 : ((cls == 8) ? 31 : 0);
  int off0 = p_lo - 128 * kr;
  int shift = off0 & 3;
  int offA  = off0 - shift;
  int rowLen = (shift + Lh + 3) & ~3;

  float* row = Hbuf + (long long)(i * C_NCLS + cls) * C_HSTRIDE + C_HGUARD;
  for (int q = threadIdx.x; q < Lh; q += 256) {
    double acc = 0.0;
    for (int t = 0; t < npv; ++t) acc += v_sh[t] * (double)kernp[q - t];
    row[shift + q] = (float)acc;
  }
  if (threadIdx.x == 0) {
    meta[(i * C_NCLS + cls) * 2 + 0] = offA;
    meta[(i * C_NCLS + cls) * 2 + 1] = rowLen;
  }
}

// ---------------- main: OT[scale][w][sig] += sum_{m in piece} xp[m][sig]*H_w[m] ----------
// grid (piece, chunk, scale'), scale' reversed so heavy scales dispatch first.
__global__ __launch_bounds__(128, 8) void k_cwt_main(const float4* __restrict__ xp4,
                                                     const float* __restrict__ Hbuf,
                                                     const int* __restrict__ meta,
                                                     float* __restrict__ OT) {
  int piece = blockIdx.x;           // 0..6
  int chunk = blockIdx.y;           // 0..55
  int i     = 127 - blockIdx.z;     // heavy scales first
  int sig   = threadIdx.x;          // 0..127 (>=96 compute zeros)

  __shared__ float4 Hs[C_RW][C_SL4];   // 8448 B

  float acc[C_RW];
  const float* rowP[C_RW];   // row base (incl. guard) in Hbuf
  int relS[C_RW];            // float index of m0 within the row, 4-aligned
  int U0 = 0x7fffffff, U1 = 0;
  int startj[C_RW];
#pragma unroll
  for (int j = 0; j < C_RW; ++j) {
    acc[j] = 0.f;
    int w = chunk * C_RW + j;
    int cls = (w == 0) ? 7 : ((w == 223) ? 8 : (w % 7));
    int k = w / 7;
    int base = i * C_NCLS + cls;
    int offA = meta[base * 2 + 0];
    int rl   = meta[base * 2 + 1];
    int start = offA + 128 * k;           // 4-aligned by construction
    startj[j] = start;
    if (start < U0) U0 = start;
    if (start + rl > U1) U1 = start + rl;
    rowP[j] = Hbuf + (long long)base * C_HSTRIDE;
  }

  int m0 = U0 + piece * C_M;
  int m1 = m0 + C_M; if (m1 > U1) m1 = U1;
  if (m0 >= m1) return;                  // uniform across block (ok w.r.t. barrier)

#pragma unroll
  for (int j = 0; j < C_RW; ++j) relS[j] = C_HGUARD + m0 - startj[j];  // in [100, 3072+160]

  // ---- stage H piece into LDS (coalesced vector loads; independent, 1 barrier) ----
  // rel stays < 3776 for all staged elements (max 3759), so reads never leave
  // the row: they hit data or the zero guards. No clamping needed.
  int sLen4 = ((m1 - m0) >> 2) + 4; if (sLen4 > C_SL4) sLen4 = C_SL4;
#pragma unroll
  for (int j = 0; j < C_RW; ++j) {
    const float* src = rowP[j] + relS[j];
    for (int q = threadIdx.x; q < sLen4; q += 128)
      Hs[j][q] = *(const float4*)(src + 4 * q);
  }
  __syncthreads();

  // ---- inner loop: x on vmcnt (global), H on lgkmcnt (LDS broadcast) ----
  int nq4 = (m1 - m0) >> 2;              // float4 steps (pairs consumed per iter)
  const float4* xr = xp4 + ((long long)(m0 >> 2) * C_SIGP + sig);
  float4 x0 = xr[0];
  float4 x1 = xr[C_SIGP];
  xr += 2 * C_SIGP;
  for (int q4 = 0; q4 < nq4; q4 += 2) {
    float4 xn0 = xr[0];                  // depth-1 x prefetch
    float4 xn1 = xr[C_SIGP];
    xr += 2 * C_SIGP;
    float4 h0[C_RW], h1[C_RW];
#pragma unroll
    for (int j = 0; j < C_RW; ++j) { h0[j] = Hs[j][q4]; h1[j] = Hs[j][q4 + 1]; }
#pragma unroll
    for (int j = 0; j < C_RW; ++j) {
      acc[j] += x0.x * h0[j].x + x0.y * h0[j].y + x0.z * h0[j].z + x0.w * h0[j].w;
      acc[j] += x1.x * h1[j].x + x1.y * h1[j].y + x1.z * h1[j].z + x1.w * h1[j].w;
    }
    x0 = xn0; x1 = xn1;
  }

#pragma unroll
  for (int j = 0; j < C_RW; ++j) {
    int w = chunk * C_RW + j;
    atomicAdd(&OT[((long long)i * C_NW + w) * C_SIGP + sig], acc[j]);
  }
}

// ---------------- final: scale-dim bilinear upsample 128->224 + layout ----------------
__global__ __launch_bounds__(256) void k_final(const float* __restrict__ OT,
                                               float* __restrict__ out) {
  int wt = blockIdx.x;    // 0..27
  int h  = blockIdx.y;    // 0..223

  float inv = 128.0f / 224.0f;               // f32 like jax
  float sg = ((float)h + 0.5f) * inv - 0.5f;
  float sgf = floorf(sg);
  int s0 = (int)sgf;
  float fr = sg - sgf;
  int r0, r1;
  if (s0 < 0)        { r0 = 0;   r1 = 0;   fr = 0.f; }
  else if (s0 >= 127){ r0 = 127; r1 = 127; fr = 0.f; }
  else               { r0 = s0;  r1 = s0 + 1; }

  __shared__ float sh0[8 * 132];
  __shared__ float sh1[8 * 132];
  for (int q = threadIdx.x; q < 1024; q += 256) {
    int wp  = q >> 7;
    int sg2 = q & 127;
    int wg  = wt * 8 + wp;
    sh0[wp * 132 + sg2] = OT[((long long)r0 * C_NW + wg) * C_SIGP + sg2];
    sh1[wp * 132 + sg2] = OT[((long long)r1 * C_NW + wg) * C_SIGP + sg2];
  }
  __syncthreads();

  int b  = threadIdx.x >> 3;    // 0..31
  int wp = threadIdx.x & 7;     // 0..7
  int obase = ((b * 224 + h) * 224 + wt * 8 + wp) * 3;
#pragma unroll
  for (int c = 0; c < 3; ++c) {
    int sidx = wp * 132 + c * 32 + b;
    float a0 = sh0[sidx];
    float a1 = sh1[sidx];
    out[obase + c] = (1.0f - fr) * a0 + fr * a1;
  }
}

// ---------------- launch ----------------
extern "C" void kernel_launch(void* const* d_in, const int* in_sizes, int n_in,
                              void* d_out, int out_size, void* d_ws, size_t ws_size,
                              hipStream_t stream) {
  const float* x       = (const float*)d_in[0];   // (32,4096,3) f32
  const float* int_psi = (const float*)d_in[1];   // (4096,) f32
  float* out = (float*)d_out;

  // workspace layout: xp4 (4 MB) | Hbuf (17.4 MB) | meta (9 KB) | OT (14.7 MB)
  float* xp4  = (float*)d_ws;                                   // 8192*128 floats
  float* Hbuf = xp4 + (long long)C_XROWS * C_SIGP;              // 1152*3776 floats
  int*   meta = (int*)(Hbuf + (long long)128 * C_NCLS * C_HSTRIDE); // 2304 ints
  float* OT   = (float*)(meta + 2304);                          // 128*224*128 floats

  int otN = 128 * C_NW * C_SIGP;
  k_zero<<<dim3(otN / 4 / 256), dim3(256), 0, stream>>>(OT, otN / 4);
  k_build_xp<<<dim3((C_XROWS * C_SIGP) / 256), dim3(256), 0, stream>>>(x, xp4);
  k_build_H<<<dim3(128, C_NCLS), dim3(256), 0, stream>>>(int_psi, Hbuf, meta);
  k_cwt_main<<<dim3(C_NP, C_NCH, 128), dim3(128), 0, stream>>>((const float4*)xp4, Hbuf, meta, OT);
  k_final<<<dim3(28, 224), dim3(256), 0, stream>>>(OT, out);
}

// Round 7
// 262.407 us; speedup vs baseline: 4.4107x; 1.0626x over previous
//
#include <hip/hip_runtime.h>
#include <cmath>
#include <cstdint>

// ---------------- static configuration ----------------
// B=32, T=4096, C=3, 128 scales, out 224x224, N_PSI=4096, pad=2047.
// sig = c*32 + b  (96 signals), padded signal length 8190 (store 8192).
// Composite kernel per (scale, class): class 0..6 = interior phase (w mod 7),
// class 7 = w==0 (left-clipped), class 8 = w==223 (right-clipped).
// H rows: [160 zero guard][<=3308 data, 4-aligned][>=308 zero guard], stride 3776 floats.
// xp stored interleaved: xp4[m>>2][sig][m&3] -> one global_load_dwordx4 per 4 m.
//
// Round 6 result: LDS-staged H hit 173 us, VALUBusy 91.7% — but arithmetic
// showed the binding pipe is LDS bandwidth: broadcast ds_read_b128 delivers
// 1 KB/wave-inst; 16 KB per 8-m block-iteration -> 11.6 GB / 69 TB/s = 168 us
// = measured duration. Round 7: halve LDS bytes per FMA. Block = 64 threads
// (1 wave); each lane owns TWO sig-slots (L and L+64), so each H quad read
// feeds 8 FMAs instead of 4. x loads remain two contiguous 1 KB wave-loads.
// Predicted floor: max(LDS ~84 us, VALU ~50 us, x-L2) ~= 95-115 us.

constexpr int C_TP     = 8190;
constexpr int C_XROWS  = 8192;   // time rows in xp
constexpr int C_SIGP   = 128;    // padded signals (96 real)
constexpr long long C_HSTRIDE = 3776;
constexpr int C_HGUARD = 160;
constexpr int C_NCLS   = 9;
constexpr int C_RW     = 4;      // w's per block
constexpr int C_NCH    = 56;     // 224 / C_RW
constexpr int C_NW     = 224;
constexpr int C_M      = 512;    // m per piece
constexpr int C_NP     = 7;      // max pieces
constexpr int C_SL4    = 132;    // staged float4 per row

// Replicate numpy: scales = logspace(log10(2), log10(204), 128).astype(f32);
// K = ceil(16*s + 1); d = (4094-K)//2; a = s * (16/4095) in double.
__device__ __forceinline__ void scale_params(int i, float& s32, int& K, int& d, double& a) {
  const double l2   = log10(2.0);
  const double l204 = log10(204.0);
  double step = (l204 - l2) / 127.0;
  double e = (i == 127) ? l204 : ((double)i * step + l2);
  double sv = pow(10.0, e);
  s32 = (float)sv;
  double sp = (double)s32;
  K = (int)ceil(sp * 16.0 + 1.0);
  d = (4094 - K) >> 1;
  a = sp * (16.0 / 4095.0);
}

// ---------------- build reflect-padded, interleaved signals ----------------
__global__ void k_build_xp(const float* __restrict__ x, float* __restrict__ xp4) {
  int idx = blockIdx.x * blockDim.x + threadIdx.x;   // 8192*128 threads
  int j    = idx & 3;
  int sig  = (idx >> 2) & 127;
  int mblk = idx >> 9;
  int p    = mblk * 4 + j;
  float val = 0.f;
  if (sig < 96 && p < C_TP) {
    int c = sig >> 5;
    int b = sig & 31;
    int t = p - 2047;
    if (t < 0) t = -t;                 // x[2047-p]
    else if (t > 4095) t = 8190 - t;   // x[10237-p]
    val = x[(b * 4096 + t) * 3 + c];
  }
  xp4[idx] = val;
}

// ---------------- zero OT (atomic accumulation target) ----------------
__global__ void k_zero(float* __restrict__ p, int n4) {
  int idx = blockIdx.x * blockDim.x + threadIdx.x;
  if (idx < n4) ((float4*)p)[idx] = make_float4(0.f, 0.f, 0.f, 0.f);
}

// ---------------- build composite kernels H ----------------
__global__ __launch_bounds__(256) void k_build_H(const float* __restrict__ int_psi,
                                                 float* __restrict__ Hbuf,
                                                 int* __restrict__ meta) {
  int i   = blockIdx.x;   // scale
  int cls = blockIdx.y;   // class

  float s32; int K, d; double a;
  scale_params(i, s32, K, d, a);

  int wr = (cls < 7) ? ((cls == 0) ? 7 : cls) : ((cls == 7) ? 0 : 223);
  double ks = 4096.0 / 224.0;
  double sf = ((double)wr + 0.5) * ks - 0.5;
  int t_lo = (int)floor(sf - ks) + 1;
  int t_hi = (int)ceil(sf + ks) - 1;
  if (t_lo < 0) t_lo = 0;
  if (t_hi > 4095) t_hi = 4095;
  int nt  = t_hi - t_lo + 1;   // <= 37
  int npv = nt + 1;            // conv-point weights

  __shared__ double Wt_sh[40];
  __shared__ double v_sh[64];
  __shared__ float  kern_sh[3352];

  // zero this block's full row
  float* rowFull = Hbuf + (long long)(i * C_NCLS + cls) * C_HSTRIDE;
  for (int q = threadIdx.x; q < (int)C_HSTRIDE; q += 256) rowFull[q] = 0.f;

  if (threadIdx.x == 0) {
    double Z = 0.0;
    for (int t = 0; t < nt; ++t) {
      double wv = 1.0 - fabs(sf - (double)(t + t_lo)) / ks;
      if (wv < 0.0) wv = 0.0;
      Wt_sh[t] = wv; Z += wv;
    }
    for (int t = 0; t < nt; ++t) Wt_sh[t] = Wt_sh[t] / Z;
    double sq = sqrt((double)s32);
    // v[p_lo + q] = -sqrt(s) * (Wt[q-1] - Wt[q])
    for (int q = 0; q <= nt; ++q) {
      double wm1 = (q >= 1)  ? Wt_sh[q - 1] : 0.0;
      double w0  = (q < nt)  ? Wt_sh[q]     : 0.0;
      v_sh[q] = -sq * (wm1 - w0);
    }
  }

  // flipped gathered wavelet: kernW[tau] = int_psi[clip(floor((K-1-tau)/a))]
  float* kernp = kern_sh + 40;
  int fillN = K + 80;
  for (int q = threadIdx.x; q < fillN; q += 256) {
    int tau = q - 40;
    float kv = 0.f;
    if (tau >= 0 && tau < K) {
      int u = K - 1 - tau;
      int jj = (int)floor((double)u / a);
      jj = jj < 0 ? 0 : (jj > 4095 ? 4095 : jj);
      kv = int_psi[jj];
    }
    kern_sh[q] = kv;
  }
  __syncthreads();

  int p_lo = t_lo + d;
  int Lh   = K + npv - 1;
  int kr   = (cls == 0) ? 1 : ((cls == 8) ? 31 : 0);
  int off0 = p_lo - 128 * kr;
  int shift = off0 & 3;
  int offA  = off0 - shift;
  int rowLen = (shift + Lh + 3) & ~3;

  float* row = Hbuf + (long long)(i * C_NCLS + cls) * C_HSTRIDE + C_HGUARD;
  for (int q = threadIdx.x; q < Lh; q += 256) {
    double acc = 0.0;
    for (int t = 0; t < npv; ++t) acc += v_sh[t] * (double)kernp[q - t];
    row[shift + q] = (float)acc;
  }
  if (threadIdx.x == 0) {
    meta[(i * C_NCLS + cls) * 2 + 0] = offA;
    meta[(i * C_NCLS + cls) * 2 + 1] = rowLen;
  }
}

// ---------------- main: OT[scale][w][slot] += sum_{m in piece} xp[m][slot]*H_w[m] --------
// grid (piece, chunk, scale'), scale' reversed so heavy scales dispatch first.
// ONE wave per block; lane owns slots (lane) and (lane+64).
__global__ __launch_bounds__(64, 8) void k_cwt_main(const float4* __restrict__ xp4,
                                                    const float* __restrict__ Hbuf,
                                                    const int* __restrict__ meta,
                                                    float* __restrict__ OT) {
  int piece = blockIdx.x;           // 0..6
  int chunk = blockIdx.y;           // 0..55
  int i     = 127 - blockIdx.z;     // heavy scales first
  int lane  = threadIdx.x;          // 0..63

  __shared__ float4 Hs[C_RW][C_SL4];   // 8448 B

  float accA[C_RW], accB[C_RW];
  const float* rowP[C_RW];   // row base (incl. guard) in Hbuf
  int relS[C_RW];            // float index of m0 within the row, 4-aligned
  int U0 = 0x7fffffff, U1 = 0;
  int startj[C_RW];
#pragma unroll
  for (int j = 0; j < C_RW; ++j) {
    accA[j] = 0.f; accB[j] = 0.f;
    int w = chunk * C_RW + j;
    int cls = (w == 0) ? 7 : ((w == 223) ? 8 : (w % 7));
    int k = w / 7;
    int base = i * C_NCLS + cls;
    int offA = meta[base * 2 + 0];
    int rl   = meta[base * 2 + 1];
    int start = offA + 128 * k;           // 4-aligned by construction
    startj[j] = start;
    if (start < U0) U0 = start;
    if (start + rl > U1) U1 = start + rl;
    rowP[j] = Hbuf + (long long)base * C_HSTRIDE;
  }

  int m0 = U0 + piece * C_M;
  int m1 = m0 + C_M; if (m1 > U1) m1 = U1;
  if (m0 >= m1) return;                  // uniform across block

#pragma unroll
  for (int j = 0; j < C_RW; ++j) relS[j] = C_HGUARD + m0 - startj[j];  // in [100, 3232]

  // ---- stage H piece into LDS (coalesced vector loads, 1 barrier) ----
  // rel stays < 3776 for all staged elements, so reads never leave the row:
  // they hit data or the zero guards. No clamping needed.
  int sLen4 = ((m1 - m0) >> 2) + 4; if (sLen4 > C_SL4) sLen4 = C_SL4;
#pragma unroll
  for (int j = 0; j < C_RW; ++j) {
    const float* src = rowP[j] + relS[j];
    for (int q = lane; q < sLen4; q += 64)
      Hs[j][q] = *(const float4*)(src + 4 * q);
  }
  __syncthreads();

  // ---- inner loop: x on vmcnt (global), H on lgkmcnt (LDS broadcast) ----
  // Each H quad feeds 8 FMAs (2 slots) -> LDS bytes/FMA halved vs round 6.
  int nq4 = (m1 - m0) >> 2;              // float4 steps (2 consumed per iter)
  const float4* xr = xp4 + ((long long)(m0 >> 2) * C_SIGP + lane);
  float4 xa0 = xr[0];                    // slot lane,    q4
  float4 xb0 = xr[64];                   // slot lane+64, q4
  float4 xa1 = xr[C_SIGP];               // slot lane,    q4+1
  float4 xb1 = xr[C_SIGP + 64];
  xr += 2 * C_SIGP;
  for (int q4 = 0; q4 < nq4; q4 += 2) {
    float4 na0 = xr[0];                  // depth-1 x prefetch
    float4 nb0 = xr[64];
    float4 na1 = xr[C_SIGP];
    float4 nb1 = xr[C_SIGP + 64];
    xr += 2 * C_SIGP;
    float4 h0[C_RW], h1[C_RW];
#pragma unroll
    for (int j = 0; j < C_RW; ++j) { h0[j] = Hs[j][q4]; h1[j] = Hs[j][q4 + 1]; }
#pragma unroll
    for (int j = 0; j < C_RW; ++j) {
      accA[j] += xa0.x * h0[j].x + xa0.y * h0[j].y + xa0.z * h0[j].z + xa0.w * h0[j].w;
      accA[j] += xa1.x * h1[j].x + xa1.y * h1[j].y + xa1.z * h1[j].z + xa1.w * h1[j].w;
      accB[j] += xb0.x * h0[j].x + xb0.y * h0[j].y + xb0.z * h0[j].z + xb0.w * h0[j].w;
      accB[j] += xb1.x * h1[j].x + xb1.y * h1[j].y + xb1.z * h1[j].z + xb1.w * h1[j].w;
    }
    xa0 = na0; xb0 = nb0; xa1 = na1; xb1 = nb1;
  }

#pragma unroll
  for (int j = 0; j < C_RW; ++j) {
    int w = chunk * C_RW + j;
    atomicAdd(&OT[((long long)i * C_NW + w) * C_SIGP + lane],      accA[j]);
    atomicAdd(&OT[((long long)i * C_NW + w) * C_SIGP + lane + 64], accB[j]);
  }
}

// ---------------- final: scale-dim bilinear upsample 128->224 + layout ----------------
__global__ __launch_bounds__(256) void k_final(const float* __restrict__ OT,
                                               float* __restrict__ out) {
  int wt = blockIdx.x;    // 0..27
  int h  = blockIdx.y;    // 0..223

  float inv = 128.0f / 224.0f;               // f32 like jax
  float sg = ((float)h + 0.5f) * inv - 0.5f;
  float sgf = floorf(sg);
  int s0 = (int)sgf;
  float fr = sg - sgf;
  int r0, r1;
  if (s0 < 0)        { r0 = 0;   r1 = 0;   fr = 0.f; }
  else if (s0 >= 127){ r0 = 127; r1 = 127; fr = 0.f; }
  else               { r0 = s0;  r1 = s0 + 1; }

  __shared__ float sh0[8 * 132];
  __shared__ float sh1[8 * 132];
  for (int q = threadIdx.x; q < 1024; q += 256) {
    int wp  = q >> 7;
    int sg2 = q & 127;
    int wg  = wt * 8 + wp;
    sh0[wp * 132 + sg2] = OT[((long long)r0 * C_NW + wg) * C_SIGP + sg2];
    sh1[wp * 132 + sg2] = OT[((long long)r1 * C_NW + wg) * C_SIGP + sg2];
  }
  __syncthreads();

  int b  = threadIdx.x >> 3;    // 0..31
  int wp = threadIdx.x & 7;     // 0..7
  int obase = ((b * 224 + h) * 224 + wt * 8 + wp) * 3;
#pragma unroll
  for (int c = 0; c < 3; ++c) {
    int sidx = wp * 132 + c * 32 + b;
    float a0 = sh0[sidx];
    float a1 = sh1[sidx];
    out[obase + c] = (1.0f - fr) * a0 + fr * a1;
  }
}

// ---------------- launch ----------------
extern "C" void kernel_launch(void* const* d_in, const int* in_sizes, int n_in,
                              void* d_out, int out_size, void* d_ws, size_t ws_size,
                              hipStream_t stream) {
  const float* x       = (const float*)d_in[0];   // (32,4096,3) f32
  const float* int_psi = (const float*)d_in[1];   // (4096,) f32
  float* out = (float*)d_out;

  // workspace layout: xp4 (4 MB) | Hbuf (17.4 MB) | meta (9 KB) | OT (14.7 MB)
  float* xp4  = (float*)d_ws;                                   // 8192*128 floats
  float* Hbuf = xp4 + (long long)C_XROWS * C_SIGP;              // 1152*3776 floats
  int*   meta = (int*)(Hbuf + (long long)128 * C_NCLS * C_HSTRIDE); // 2304 ints
  float* OT   = (float*)(meta + 2304);                          // 128*224*128 floats

  int otN = 128 * C_NW * C_SIGP;
  k_zero<<<dim3(otN / 4 / 256), dim3(256), 0, stream>>>(OT, otN / 4);
  k_build_xp<<<dim3((C_XROWS * C_SIGP) / 256), dim3(256), 0, stream>>>(x, xp4);
  k_build_H<<<dim3(128, C_NCLS), dim3(256), 0, stream>>>(int_psi, Hbuf, meta);
  k_cwt_main<<<dim3(C_NP, C_NCH, 128), dim3(64), 0, stream>>>((const float4*)xp4, Hbuf, meta, OT);
  k_final<<<dim3(28, 224), dim3(256), 0, stream>>>(OT, out);
}

// Round 8
// 230.869 us; speedup vs baseline: 5.0132x; 1.1366x over previous
//
#include <hip/hip_runtime.h>
#include <cmath>
#include <cstdint>

// ---------------- static configuration ----------------
// B=32, T=4096, C=3, 128 scales, out 224x224, N_PSI=4096, pad=2047.
// slot = c*32 + b (96 real, padded to 128), padded signal length 8190.
// Composite kernel per (scale, class): class 0..6 = interior phase (w mod 7),
// class 7 = w==0 (left-clipped), class 8 = w==223 (right-clipped).
// H rows: [160 zero guard][<=3308 data, 4-aligned][>=308 zero guard], stride 3776.
//
// x layout (round 8): PAIR-INTERLEAVED for v_pk_fma_f32:
//   xpP[mp][lane][4] = { xp[2mp][lane], xp[2mp][lane+64], xp[2mp+1][lane], xp[2mp+1][lane+64] }
// so one 16-B lane load yields two ALIGNED (slotA,slotB) register pairs and
// acc2 += pair * h_scalar lowers to packed-dual FP32 FMA (157-TF rate) with
// zero packing movs.
//
// Round 7 post-mortem: VALU-issue was the binding pipe (126 us busy vs 45 us
// useful FMA) — manual prefetch-rotate movs + unpacked FMA. Round 8: packed
// FMA (halves FMA issue), no manual rotate (compiler renames via unroll),
// exact 4-m steps. LDS broadcast-bus floor for this structure: ~68 us.

constexpr int C_TP     = 8190;
constexpr int C_XROWS  = 8192;   // time rows in xp
constexpr long long C_HSTRIDE = 3776;
constexpr int C_HGUARD = 160;
constexpr int C_NCLS   = 9;
constexpr int C_RW     = 4;      // w's per block
constexpr int C_NCH    = 56;     // 224 / C_RW
constexpr int C_NW     = 224;
constexpr int C_SIGP   = 128;    // padded slots
constexpr int C_M      = 512;    // m per piece
constexpr int C_NP     = 7;      // max pieces
constexpr int C_SL4    = 128;    // staged quads per row (C_M/4)

typedef float v2f __attribute__((ext_vector_type(2)));
typedef float v4f __attribute__((ext_vector_type(4)));

// Replicate numpy: scales = logspace(log10(2), log10(204), 128).astype(f32);
// K = ceil(16*s + 1); d = (4094-K)//2; a = s * (16/4095) in double.
__device__ __forceinline__ void scale_params(int i, float& s32, int& K, int& d, double& a) {
  const double l2   = log10(2.0);
  const double l204 = log10(204.0);
  double step = (l204 - l2) / 127.0;
  double e = (i == 127) ? l204 : ((double)i * step + l2);
  double sv = pow(10.0, e);
  s32 = (float)sv;
  double sp = (double)s32;
  K = (int)ceil(sp * 16.0 + 1.0);
  d = (4094 - K) >> 1;
  a = sp * (16.0 / 4095.0);
}

// ---------------- build reflect-padded, pair-interleaved signals ----------------
// xpP element idx = mp*256 + lane*4 + e ; e0:(2mp,lane) e1:(2mp,lane+64)
//                                         e2:(2mp+1,lane) e3:(2mp+1,lane+64)
__global__ void k_build_xp(const float* __restrict__ x, float* __restrict__ xpP) {
  int idx  = blockIdx.x * blockDim.x + threadIdx.x;   // 4096*256 threads
  int e    = idx & 3;
  int lane = (idx >> 2) & 63;
  int mp   = idx >> 8;
  int p    = mp * 2 + (e >> 1);
  int s    = lane + 64 * (e & 1);
  float val = 0.f;
  if (s < 96 && p < C_TP) {
    int c = s >> 5;
    int b = s & 31;
    int t = p - 2047;
    if (t < 0) t = -t;                 // x[2047-p]
    else if (t > 4095) t = 8190 - t;   // x[10237-p]
    val = x[(b * 4096 + t) * 3 + c];
  }
  xpP[idx] = val;
}

// ---------------- build composite kernels H ----------------
__global__ __launch_bounds__(256) void k_build_H(const float* __restrict__ int_psi,
                                                 float* __restrict__ Hbuf,
                                                 int* __restrict__ meta) {
  int i   = blockIdx.x;   // scale
  int cls = blockIdx.y;   // class

  float s32; int K, d; double a;
  scale_params(i, s32, K, d, a);

  int wr = (cls < 7) ? ((cls == 0) ? 7 : cls) : ((cls == 7) ? 0 : 223);
  double ks = 4096.0 / 224.0;
  double sf = ((double)wr + 0.5) * ks - 0.5;
  int t_lo = (int)floor(sf - ks) + 1;
  int t_hi = (int)ceil(sf + ks) - 1;
  if (t_lo < 0) t_lo = 0;
  if (t_hi > 4095) t_hi = 4095;
  int nt  = t_hi - t_lo + 1;   // <= 37
  int npv = nt + 1;            // conv-point weights

  __shared__ double Wt_sh[40];
  __shared__ double v_sh[64];
  __shared__ float  kern_sh[3352];

  // zero this block's full row
  float* rowFull = Hbuf + (long long)(i * C_NCLS + cls) * C_HSTRIDE;
  for (int q = threadIdx.x; q < (int)C_HSTRIDE; q += 256) rowFull[q] = 0.f;

  if (threadIdx.x == 0) {
    double Z = 0.0;
    for (int t = 0; t < nt; ++t) {
      double wv = 1.0 - fabs(sf - (double)(t + t_lo)) / ks;
      if (wv < 0.0) wv = 0.0;
      Wt_sh[t] = wv; Z += wv;
    }
    for (int t = 0; t < nt; ++t) Wt_sh[t] = Wt_sh[t] / Z;
    double sq = sqrt((double)s32);
    // v[p_lo + q] = -sqrt(s) * (Wt[q-1] - Wt[q])
    for (int q = 0; q <= nt; ++q) {
      double wm1 = (q >= 1)  ? Wt_sh[q - 1] : 0.0;
      double w0  = (q < nt)  ? Wt_sh[q]     : 0.0;
      v_sh[q] = -sq * (wm1 - w0);
    }
  }

  // flipped gathered wavelet: kernW[tau] = int_psi[clip(floor((K-1-tau)/a))]
  float* kernp = kern_sh + 40;
  int fillN = K + 80;
  for (int q = threadIdx.x; q < fillN; q += 256) {
    int tau = q - 40;
    float kv = 0.f;
    if (tau >= 0 && tau < K) {
      int u = K - 1 - tau;
      int jj = (int)floor((double)u / a);
      jj = jj < 0 ? 0 : (jj > 4095 ? 4095 : jj);
      kv = int_psi[jj];
    }
    kern_sh[q] = kv;
  }
  __syncthreads();

  int p_lo = t_lo + d;
  int Lh   = K + npv - 1;
  int kr   = (cls == 0) ? 1 : ((cls == 8) ? 31 : 0);
  int off0 = p_lo - 128 * kr;
  int shift = off0 & 3;
  int offA  = off0 - shift;
  int rowLen = (shift + Lh + 3) & ~3;

  float* row = Hbuf + (long long)(i * C_NCLS + cls) * C_HSTRIDE + C_HGUARD;
  for (int q = threadIdx.x; q < Lh; q += 256) {
    double acc = 0.0;
    for (int t = 0; t < npv; ++t) acc += v_sh[t] * (double)kernp[q - t];
    row[shift + q] = (float)acc;
  }
  if (threadIdx.x == 0) {
    meta[(i * C_NCLS + cls) * 2 + 0] = offA;
    meta[(i * C_NCLS + cls) * 2 + 1] = rowLen;
  }
}

// ---------------- main: OT[scale][w][slot] += sum_{m in piece} xp[m][slot]*H_w[m] --------
// grid (piece, chunk, scale'), scale' reversed so heavy scales dispatch first.
// ONE wave per block; lane owns slots (lane) and (lane+64) as a packed pair.
__global__ __launch_bounds__(64, 8) void k_cwt_main(const float* __restrict__ xpP,
                                                    const float* __restrict__ Hbuf,
                                                    const int* __restrict__ meta,
                                                    float* __restrict__ OT) {
  int piece = blockIdx.x;           // 0..6
  int chunk = blockIdx.y;           // 0..55
  int i     = 127 - blockIdx.z;     // heavy scales first
  int lane  = threadIdx.x;          // 0..63

  __shared__ v4f Hs[C_RW][C_SL4];   // 8192 B

  v2f acc2[C_RW];
  const float* rowP[C_RW];   // row base (incl. guard) in Hbuf
  int U0 = 0x7fffffff, U1 = 0;
  int startj[C_RW];
#pragma unroll
  for (int j = 0; j < C_RW; ++j) {
    acc2[j] = (v2f){0.f, 0.f};
    int w = chunk * C_RW + j;
    int cls = (w == 0) ? 7 : ((w == 223) ? 8 : (w % 7));
    int k = w / 7;
    int base = i * C_NCLS + cls;
    int offA = meta[base * 2 + 0];
    int rl   = meta[base * 2 + 1];
    int start = offA + 128 * k;           // 4-aligned by construction
    startj[j] = start;
    if (start < U0) U0 = start;
    if (start + rl > U1) U1 = start + rl;
    rowP[j] = Hbuf + (long long)base * C_HSTRIDE;
  }

  int m0 = U0 + piece * C_M;
  int m1 = m0 + C_M; if (m1 > U1) m1 = U1;
  if (m0 >= m1) return;                  // uniform across block

  // ---- stage H piece into LDS (coalesced vector loads, 1 barrier) ----
  // rel index stays < 3776 for all staged quads (data or zero guard).
  int nIter = (m1 - m0) >> 2;            // exact: m0,m1 both 4-aligned
#pragma unroll
  for (int j = 0; j < C_RW; ++j) {
    const float* src = rowP[j] + (C_HGUARD + m0 - startj[j]);
    for (int q = lane; q < nIter; q += 64)
      Hs[j][q] = *(const v4f*)(src + 4 * q);
  }
  __syncthreads();

  // ---- inner loop: 4 m per step; x on vmcnt, H broadcast on lgkmcnt ----
  // xa = {A(m),B(m),A(m+1),B(m+1)}, xb = same for m+2,m+3.
  // acc2[j] += pair * h_scalar -> v_pk_fma_f32 (packed-dual fp32).
  const float* xr = xpP + ((long long)(m0 >> 1) * 256 + lane * 4);
#pragma unroll 2
  for (int it = 0; it < nIter; ++it) {
    v4f xa = *(const v4f*)(xr);
    v4f xb = *(const v4f*)(xr + 256);
    xr += 512;
#pragma unroll
    for (int j = 0; j < C_RW; ++j) {
      v4f h = Hs[j][it];
      acc2[j] += xa.xy * h.x;
      acc2[j] += xa.zw * h.y;
      acc2[j] += xb.xy * h.z;
      acc2[j] += xb.zw * h.w;
    }
  }

#pragma unroll
  for (int j = 0; j < C_RW; ++j) {
    int w = chunk * C_RW + j;
    atomicAdd(&OT[((long long)i * C_NW + w) * C_SIGP + lane],      acc2[j].x);
    atomicAdd(&OT[((long long)i * C_NW + w) * C_SIGP + lane + 64], acc2[j].y);
  }
}

// ---------------- final: scale-dim bilinear upsample 128->224 + layout ----------------
__global__ __launch_bounds__(256) void k_final(const float* __restrict__ OT,
                                               float* __restrict__ out) {
  int wt = blockIdx.x;    // 0..27
  int h  = blockIdx.y;    // 0..223

  float inv = 128.0f / 224.0f;               // f32 like jax
  float sg = ((float)h + 0.5f) * inv - 0.5f;
  float sgf = floorf(sg);
  int s0 = (int)sgf;
  float fr = sg - sgf;
  int r0, r1;
  if (s0 < 0)        { r0 = 0;   r1 = 0;   fr = 0.f; }
  else if (s0 >= 127){ r0 = 127; r1 = 127; fr = 0.f; }
  else               { r0 = s0;  r1 = s0 + 1; }

  __shared__ float sh0[8 * 132];
  __shared__ float sh1[8 * 132];
  for (int q = threadIdx.x; q < 1024; q += 256) {
    int wp  = q >> 7;
    int sg2 = q & 127;
    int wg  = wt * 8 + wp;
    sh0[wp * 132 + sg2] = OT[((long long)r0 * C_NW + wg) * C_SIGP + sg2];
    sh1[wp * 132 + sg2] = OT[((long long)r1 * C_NW + wg) * C_SIGP + sg2];
  }
  __syncthreads();

  int b  = threadIdx.x >> 3;    // 0..31
  int wp = threadIdx.x & 7;     // 0..7
  int obase = ((b * 224 + h) * 224 + wt * 8 + wp) * 3;
#pragma unroll
  for (int c = 0; c < 3; ++c) {
    int sidx = wp * 132 + c * 32 + b;
    float a0 = sh0[sidx];
    float a1 = sh1[sidx];
    out[obase + c] = (1.0f - fr) * a0 + fr * a1;
  }
}

// ---------------- launch ----------------
extern "C" void kernel_launch(void* const* d_in, const int* in_sizes, int n_in,
                              void* d_out, int out_size, void* d_ws, size_t ws_size,
                              hipStream_t stream) {
  const float* x       = (const float*)d_in[0];   // (32,4096,3) f32
  const float* int_psi = (const float*)d_in[1];   // (4096,) f32
  float* out = (float*)d_out;

  // workspace layout: xpP (4 MB) | Hbuf (17.4 MB) | meta (9 KB) | OT (14.7 MB)
  float* xpP  = (float*)d_ws;                                   // 8192*128 floats
  float* Hbuf = xpP + (long long)C_XROWS * C_SIGP;              // 1152*3776 floats
  int*   meta = (int*)(Hbuf + (long long)128 * C_NCLS * C_HSTRIDE); // 2304 ints
  float* OT   = (float*)(meta + 2304);                          // 128*224*128 floats

  hipMemsetAsync(OT, 0, (size_t)128 * C_NW * C_SIGP * sizeof(float), stream);
  k_build_xp<<<dim3((C_XROWS / 2 * 256) / 256), dim3(256), 0, stream>>>(x, xpP);
  k_build_H<<<dim3(128, C_NCLS), dim3(256), 0, stream>>>(int_psi, Hbuf, meta);
  k_cwt_main<<<dim3(C_NP, C_NCH, 128), dim3(64), 0, stream>>>(xpP, Hbuf, meta, OT);
  k_final<<<dim3(28, 224), dim3(256), 0, stream>>>(OT, out);
}